// Round 8
// baseline (1161.242 us; speedup 1.0000x reference)
//
#include <hip/hip_runtime.h>

#define DIM 128
#define NCB 8
#define KSZ 2048
#define BATCH 16
#define TOK 2048
#define NTOK (BATCH * TOK)            // 32768
#define NELEM (BATCH * DIM * TOK)     // 4194304
#define T_TILE 64                     // tokens per block
#define NTHR 512                      // 8 waves; wave-pair shares 16 tokens,
                                      // each wave sweeps half the codebook
#define NRG 64                        // 16-code rowgroups per half (1024/16)

typedef float f32x4 __attribute__((ext_vector_type(4)));
typedef short s16x8 __attribute__((ext_vector_type(8)));

__device__ __forceinline__ unsigned short f2bf(float f) {
    unsigned u = __float_as_uint(f);
    u = (u + 0x7FFFu + ((u >> 16) & 1u)) >> 16;   // RNE, finite inputs only
    return (unsigned short)u;
}
__device__ __forceinline__ float bf2f(unsigned short h) {
    return __uint_as_float(((unsigned)h) << 16);
}

// ---------------------------------------------------------------------------
// prep: codebooks -> bf16 hi plane only
// ---------------------------------------------------------------------------
__global__ void rvq_prep_hi(const float* __restrict__ cbs,
                            unsigned short* __restrict__ ch) {
    int i = blockIdx.x * 256 + threadIdx.x;
    ch[i] = f2bf(cbs[i]);
}

// ---------------------------------------------------------------------------
// exact fp32 cnorm + zero loss accumulator
// ---------------------------------------------------------------------------
__global__ void rvq_cnorm(const float* __restrict__ cbs,
                          float* __restrict__ cnorm,
                          float* __restrict__ loss_acc) {
    if (blockIdx.x == 0 && threadIdx.x == 0) *loss_acc = 0.0f;
    int k = blockIdx.x * 256 + threadIdx.x;
    const float4* row = (const float4*)(cbs + (size_t)k * DIM);
    float s = 0.0f;
#pragma unroll
    for (int i = 0; i < DIM / 4; ++i) {
        float4 v = row[i];
        s += v.x * v.x + v.y * v.y + v.z * v.z + v.w * v.w;
    }
    cnorm[k] = s;
}

// ---------------------------------------------------------------------------
// fused RVQ. 8 waves/block, T_TILE=64, grid=512, LDS 58 KB -> 2 blocks/CU =
// 16 waves/CU. Wave wv: wg=wv>>1 owns tokens wg*16..+15, h2=wv&1 sweeps
// codebook half h2.
// KEY CHANGE vs r7: the sweep is BARRIER-FREE. B-fragments are loaded
// directly global->registers (the r7 LDS round-trip was an identity per
// lane; LDS only amplified bandwidth 4x at the cost of 2 barriers/chunk
// that phase-locked all waves -> pipes serialized, all <50% busy at 555us).
// Codebook is L2-resident; 2-rg double-buffer hides load latency; waves
// drift freely so VMEM/MFMA/VALU overlap across the 4 waves/SIMD.
// Fold: per-rg insertion -> exact per-(class,half) top-2 (pool quality >=
// round-6's passing config). Publish/merge/rescore are r7 VERBATIM
// (rn-inclusive exact fp32 rescore: reproduces reference rounding).
// ---------------------------------------------------------------------------
__global__ __launch_bounds__(NTHR, 4) void rvq_fused(
        const float* __restrict__ x,            // (B, D, T)
        const float* __restrict__ cbs,          // (NCB, KSZ, DIM) fp32
        const unsigned short* __restrict__ ch,  // bf16 hi
        const float* __restrict__ cng,          // (NCB*KSZ) exact cnorm
        float* __restrict__ out,                // (B, D, T)
        float* __restrict__ codes,              // (B, NCB, T) as float
        float* __restrict__ loss_acc) {
    __shared__ float res_lds[T_TILE][DIM + 2];     // 33280 B
    __shared__ float mv1[T_TILE * 32];             // 8192 B
    __shared__ float mv2[T_TILE * 32];             // 8192 B
    __shared__ unsigned short mi1[T_TILE * 32];    // 4096 B
    __shared__ unsigned short mi2[T_TILE * 32];    // 4096 B
    __shared__ unsigned short best4s[T_TILE][4];   // 512 B => 58368 B

    const int tid   = threadIdx.x;
    const int lane  = tid & 63;
    const int wv    = __builtin_amdgcn_readfirstlane(tid >> 6);  // 0..7
    const int col16 = lane & 15;
    const int quad  = lane >> 4;
    const int h2    = wv & 1;          // codebook half this wave sweeps
    const int wg    = wv >> 1;         // token group (0..3)

    const int token0 = blockIdx.x * T_TILE;
    const int b      = token0 >> 11;
    const int t_in_b = token0 & (TOK - 1);

    // ---- init: x[b][d][t0..] -> res_lds[t][d] ----
    {
        const float* xb = x + (size_t)b * DIM * TOK + t_in_b;
#pragma unroll
        for (int it = 0; it < 4; ++it) {
            int idx = it * NTHR + tid;           // 0..2047
            int d  = idx >> 4;
            int t4 = (idx & 15) * 4;
            float4 v = *(const float4*)(xb + (size_t)d * TOK + t4);
            res_lds[t4 + 0][d] = v.x;
            res_lds[t4 + 1][d] = v.y;
            res_lds[t4 + 2][d] = v.z;
            res_lds[t4 + 3][d] = v.w;
        }
    }
    __syncthreads();

    float my_loss = 0.0f;

// load rowgroup rg's B-fragments (4 x s16x8) + cnorm straight into registers.
// Per lane: code row = h2*1024 + rg*16 + col16, dims dc*32 + quad*8.
// (Identical operand values to r7's LDS-staged path, minus the round-trip.)
#define LOADRG(buf, cnreg, rg)                                                 \
    {                                                                          \
        const unsigned short* _p = pB + (size_t)(rg) * (16 * DIM);             \
        buf[0] = *(const s16x8*)(_p + 0);                                      \
        buf[1] = *(const s16x8*)(_p + 32);                                     \
        buf[2] = *(const s16x8*)(_p + 64);                                     \
        buf[3] = *(const s16x8*)(_p + 96);                                     \
        cnreg = pCN[(rg) * 16];                                                \
    }

// 8 MFMA (hi/lo chains) over 16 tokens x 16 codes, then fold+insert.
// Order: MFMAs consume buf -> refill issued (WAR clears at MFMA issue) ->
// fold runs while refill is in flight.
#define COMPUTE_RG(buf, cnreg, rg, REFILL)                                     \
    {                                                                          \
        f32x4 axh = (f32x4){0.f, 0.f, 0.f, 0.f};                               \
        f32x4 axl = (f32x4){0.f, 0.f, 0.f, 0.f};                               \
        axh = __builtin_amdgcn_mfma_f32_16x16x32_bf16(ah[0], buf[0], axh, 0, 0, 0); \
        axl = __builtin_amdgcn_mfma_f32_16x16x32_bf16(al[0], buf[0], axl, 0, 0, 0); \
        axh = __builtin_amdgcn_mfma_f32_16x16x32_bf16(ah[1], buf[1], axh, 0, 0, 0); \
        axl = __builtin_amdgcn_mfma_f32_16x16x32_bf16(al[1], buf[1], axl, 0, 0, 0); \
        axh = __builtin_amdgcn_mfma_f32_16x16x32_bf16(ah[2], buf[2], axh, 0, 0, 0); \
        axl = __builtin_amdgcn_mfma_f32_16x16x32_bf16(al[2], buf[2], axl, 0, 0, 0); \
        axh = __builtin_amdgcn_mfma_f32_16x16x32_bf16(ah[3], buf[3], axh, 0, 0, 0); \
        axl = __builtin_amdgcn_mfma_f32_16x16x32_bf16(al[3], buf[3], axl, 0, 0, 0); \
        const float _cnu = cnreg;                                              \
        const int _idx = h2 * 1024 + (rg) * 16 + col16;                        \
        REFILL;                                                                \
        f32x4 ax = axh + axl;                                                  \
        _Pragma("unroll")                                                      \
        for (int r = 0; r < 4; ++r) {                                          \
            float p = fmaf(-2.0f, ax[r], _cnu);                                \
            bool b1 = p < v1[r];                                               \
            bool b2 = p < v2[r];                                               \
            v2[r] = b1 ? v1[r] : (b2 ? p : v2[r]);                             \
            i2[r] = b1 ? i1[r] : (b2 ? _idx : i2[r]);                          \
            v1[r] = b1 ? p : v1[r];                                            \
            i1[r] = b1 ? _idx : i1[r];                                         \
        }                                                                      \
    }

#pragma unroll 1
    for (int s = 0; s < NCB; ++s) {
        const unsigned short* __restrict__ ch_s = ch  + (size_t)s * KSZ * DIM;
        const float* __restrict__ cb_s = cbs + (size_t)s * KSZ * DIM;
        const float* __restrict__ cn_s = cng + (size_t)s * KSZ;

        const unsigned short* pB =
            ch_s + (size_t)(h2 * 1024 + col16) * DIM + quad * 8;
        const float* pCN = cn_s + h2 * 1024 + col16;

        // ---- A fragments (hi+lo) from the exact fp32 LDS residual ----
        s16x8 ah[4], al[4];
#pragma unroll
        for (int dc = 0; dc < 4; ++dc) {
            int t  = wg * 16 + col16;
            int d0 = dc * 32 + quad * 8;
            float4 u = *(const float4*)&res_lds[t][d0];
            float4 w = *(const float4*)&res_lds[t][d0 + 4];
            float e[8] = {u.x, u.y, u.z, u.w, w.x, w.y, w.z, w.w};
            s16x8 hv, lv;
#pragma unroll
            for (int j = 0; j < 8; ++j) {
                unsigned short hb = f2bf(e[j]);
                hv[j] = (short)hb;
                lv[j] = (short)f2bf(e[j] - bf2f(hb));
            }
            ah[dc] = hv; al[dc] = lv;
        }

        float v1[4], v2[4]; int i1[4], i2[4];
#pragma unroll
        for (int r = 0; r < 4; ++r) {
            v1[r] = 3.4e38f; v2[r] = 3.4e38f; i1[r] = 0; i2[r] = 0;
        }

        // ---- barrier-free sweep: 64 rowgroups, 2-buffer pipeline ----
        s16x8 bA[4], bB[4];
        float cnA, cnB;
        LOADRG(bA, cnA, 0);
        LOADRG(bB, cnB, 1);
#pragma unroll 1
        for (int rg = 0; rg < NRG; rg += 2) {
            COMPUTE_RG(bA, cnA, rg,
                       if (rg + 2 < NRG) { LOADRG(bA, cnA, rg + 2); });
            COMPUTE_RG(bB, cnB, rg + 1,
                       if (rg + 3 < NRG) { LOADRG(bB, cnB, rg + 3); });
        }

        // ---- publish per-lane top-2 (token rows of width 32) ----
#pragma unroll
        for (int r = 0; r < 4; ++r) {
            int t = wg * 16 + quad * 4 + r;
            int o = t * 32 + h2 * 16 + col16;
            mv1[o] = v1[r];
            mi1[o] = (unsigned short)i1[r];
            mv2[o] = v2[r];
            mi2[o] = (unsigned short)i2[r];
        }
        __syncthreads();

        // ---- merge 64 candidates -> top-4: 8 thr/token, 8 cands each ----
        {
            const int mt = tid >> 3;      // 0..63
            const int c8 = tid & 7;
            float bv[4] = {3.4e38f, 3.4e38f, 3.4e38f, 3.4e38f};
            int   bi[4] = {0x7FFFFFFF, 0x7FFFFFFF, 0x7FFFFFFF, 0x7FFFFFFF};
            const float* MV = (c8 & 4) ? mv2 : mv1;
            const unsigned short* MI = (c8 & 4) ? mi2 : mi1;
            const int base = mt * 32 + (c8 & 3) * 8;
            const float4 va = *(const float4*)&MV[base];
            const float4 vb = *(const float4*)&MV[base + 4];
            const s16x8  qi = *(const s16x8*)&MI[base];
            float vv[8] = {va.x, va.y, va.z, va.w, vb.x, vb.y, vb.z, vb.w};
#pragma unroll
            for (int c = 0; c < 8; ++c) {
                float v = vv[c]; int i = (int)(unsigned short)qi[c];
#pragma unroll
                for (int j = 0; j < 4; ++j) {
                    if (v < bv[j] || (v == bv[j] && i < bi[j])) {
                        float tv = bv[j]; bv[j] = v; v = tv;
                        int   ti = bi[j]; bi[j] = i; i = ti;
                    }
                }
            }
#pragma unroll
            for (int mk = 1; mk <= 4; mk <<= 1) {
                float ov[4]; int oi[4];
#pragma unroll
                for (int j = 0; j < 4; ++j) {
                    ov[j] = __shfl_xor(bv[j], mk, 64);
                    oi[j] = __shfl_xor(bi[j], mk, 64);
                }
#pragma unroll
                for (int c = 0; c < 4; ++c) {
                    float v = ov[c]; int i = oi[c];
#pragma unroll
                    for (int j = 0; j < 4; ++j) {
                        if (v < bv[j] || (v == bv[j] && i < bi[j])) {
                            float tv = bv[j]; bv[j] = v; v = tv;
                            int   ti = bi[j]; bi[j] = i; i = ti;
                        }
                    }
                }
            }
            if (c8 < 4) best4s[mt][c8] = (unsigned short)bi[c8];
        }
        __syncthreads();

        // ---- exact fp32 rescore (rn-inclusive, r7 VERBATIM):
        //      8 thr/token; groups c8<4 / c8>=4 redundantly rescore cands 0-3
        {
            const int t  = tid >> 3;
            const int c8 = tid & 7;
            const int cand = best4s[t][c8 & 3];
            const float* crow = cb_s + (size_t)cand * DIM;
            float n0 = 0, n1 = 0, n2 = 0, n3 = 0;
            float a0 = 0, a1 = 0, a2 = 0, a3 = 0;
#pragma unroll 8
            for (int d4 = 0; d4 < DIM / 4; ++d4) {
                float4 r4 = *(const float4*)&res_lds[t][d4 * 4];
                float4 q4 = *(const float4*)&crow[d4 * 4];
                n0 = fmaf(r4.x, r4.x, n0); n1 = fmaf(r4.y, r4.y, n1);
                n2 = fmaf(r4.z, r4.z, n2); n3 = fmaf(r4.w, r4.w, n3);
                a0 = fmaf(r4.x, q4.x, a0); a1 = fmaf(r4.y, q4.y, a1);
                a2 = fmaf(r4.z, q4.z, a2); a3 = fmaf(r4.w, q4.w, a3);
            }
            float rn  = (n0 + n1) + (n2 + n3);
            float dot = (a0 + a1) + (a2 + a3);
            float dist = fmaf(-2.0f, dot, rn) + cn_s[cand];
            int best = cand;
#pragma unroll
            for (int mk = 1; mk <= 2; mk <<= 1) {
                float od = __shfl_xor(dist, mk, 64);
                int   oi = __shfl_xor(best, mk, 64);
                if (od < dist || (od == dist && oi < best)) {
                    dist = od; best = oi;
                }
            }
            if (c8 == 0)
                codes[(size_t)b * (NCB * TOK) + (size_t)s * TOK + t_in_b + t] =
                    (float)best;
            // update my 16-dim slice of the token's residual + loss partial
            const float* qrow = cb_s + (size_t)best * DIM;
            float lp = 0.0f;
#pragma unroll
            for (int k4 = 0; k4 < 4; ++k4) {
                int d = c8 * 16 + k4 * 4;
                float4 r4 = *(const float4*)&res_lds[t][d];
                float4 q4 = *(const float4*)&qrow[d];
                float4 nr;
                nr.x = r4.x - q4.x; nr.y = r4.y - q4.y;
                nr.z = r4.z - q4.z; nr.w = r4.w - q4.w;
                *(float4*)&res_lds[t][d] = nr;
                lp += nr.x * nr.x + nr.y * nr.y + nr.z * nr.z + nr.w * nr.w;
            }
            my_loss += lp;
        }
        __syncthreads();
    }

    // ---- epilogue: out[b][d][t] = x - residual ----
    {
        const float* xb = x + (size_t)b * DIM * TOK + t_in_b;
        float* ob = out + (size_t)b * DIM * TOK + t_in_b;
#pragma unroll
        for (int it = 0; it < 4; ++it) {
            int idx = it * NTHR + tid;
            int d  = idx >> 4;
            int t4 = (idx & 15) * 4;
            float4 v = *(const float4*)(xb + (size_t)d * TOK + t4);
            float4 o;
            o.x = v.x - res_lds[t4 + 0][d];
            o.y = v.y - res_lds[t4 + 1][d];
            o.z = v.z - res_lds[t4 + 2][d];
            o.w = v.w - res_lds[t4 + 3][d];
            *(float4*)(ob + (size_t)d * TOK + t4) = o;
        }
    }

    // ---- loss reduction ----
#pragma unroll
    for (int off = 32; off > 0; off >>= 1)
        my_loss += __shfl_down(my_loss, off, 64);
    if (lane == 0) atomicAdd(loss_acc, my_loss);
}

// ---------------------------------------------------------------------------
__global__ void rvq_loss_fin(const float* __restrict__ loss_acc,
                             float* __restrict__ loss_out) {
    *loss_out = *loss_acc * (1.0f / (float)NELEM);
}

// ---------------------------------------------------------------------------
extern "C" void kernel_launch(void* const* d_in, const int* in_sizes, int n_in,
                              void* d_out, int out_size, void* d_ws, size_t ws_size,
                              hipStream_t stream) {
    const float* x   = (const float*)d_in[0];   // (B, D, T)
    const float* cbs = (const float*)d_in[1];   // (NCB, KSZ, DIM)

    float* out      = (float*)d_out;
    float* codes    = out + NELEM;
    float* loss_out = out + NELEM + (size_t)BATCH * NCB * TOK;

    float* wsf      = (float*)d_ws;
    float* loss_acc = wsf;
    unsigned short* ch = (unsigned short*)(wsf + 256);
    float* cng = (float*)(ch + (size_t)NCB * KSZ * DIM);

    hipLaunchKernelGGL(rvq_prep_hi, dim3((NCB * KSZ * DIM) / 256), dim3(256),
                       0, stream, cbs, ch);
    hipLaunchKernelGGL(rvq_cnorm, dim3((NCB * KSZ) / 256), dim3(256), 0, stream,
                       cbs, cng, loss_acc);
    hipLaunchKernelGGL(rvq_fused, dim3(NTOK / T_TILE), dim3(NTHR), 0, stream,
                       x, cbs, ch, cng, out, codes, loss_acc);
    hipLaunchKernelGGL(rvq_loss_fin, dim3(1), dim3(1), 0, stream,
                       loss_acc, loss_out);
}

// Round 9
// 760.728 us; speedup vs baseline: 1.5265x; 1.5265x over previous
//
#include <hip/hip_runtime.h>

#define DIM 128
#define NCB 8
#define KSZ 2048
#define BATCH 16
#define TOK 2048
#define NTOK (BATCH * TOK)            // 32768
#define NELEM (BATCH * DIM * TOK)     // 4194304
#define T_TILE 32                     // tokens per block
#define NTHR 128                      // 2 waves; wave owns 16 tokens, sweeps
                                      // the FULL codebook
#define CHUNK 64
#define NCHUNK (KSZ / CHUNK)          // 32

typedef float f32x4 __attribute__((ext_vector_type(4)));
typedef short s16x8 __attribute__((ext_vector_type(8)));

__device__ __forceinline__ unsigned short f2bf(float f) {
    unsigned u = __float_as_uint(f);
    u = (u + 0x7FFFu + ((u >> 16) & 1u)) >> 16;   // RNE, finite inputs only
    return (unsigned short)u;
}
__device__ __forceinline__ float bf2f(unsigned short h) {
    return __uint_as_float(((unsigned)h) << 16);
}

// async global -> LDS, 16 B per lane. lds base must be wave-uniform.
__device__ __forceinline__ void gll16(const void* g, void* l) {
    __builtin_amdgcn_global_load_lds(
        (const __attribute__((address_space(1))) unsigned int*)g,
        (__attribute__((address_space(3))) unsigned int*)l, 16, 0, 0);
}

// ---------------------------------------------------------------------------
// prep: codebooks -> bf16 hi plane only
// ---------------------------------------------------------------------------
__global__ void rvq_prep_hi(const float* __restrict__ cbs,
                            unsigned short* __restrict__ ch) {
    int i = blockIdx.x * 256 + threadIdx.x;
    ch[i] = f2bf(cbs[i]);
}

// ---------------------------------------------------------------------------
// exact fp32 cnorm + zero loss accumulator
// ---------------------------------------------------------------------------
__global__ void rvq_cnorm(const float* __restrict__ cbs,
                          float* __restrict__ cnorm,
                          float* __restrict__ loss_acc) {
    if (blockIdx.x == 0 && threadIdx.x == 0) *loss_acc = 0.0f;
    int k = blockIdx.x * 256 + threadIdx.x;
    const float4* row = (const float4*)(cbs + (size_t)k * DIM);
    float s = 0.0f;
#pragma unroll
    for (int i = 0; i < DIM / 4; ++i) {
        float4 v = row[i];
        s += v.x * v.x + v.y * v.y + v.z * v.z + v.w * v.w;
    }
    cnorm[k] = s;
}

// ---------------------------------------------------------------------------
// fused RVQ. 2-wave blocks, T_TILE=32, grid=1024, LDS 33 KB -> 4 blocks/CU
// (8 waves/CU like the 495us best, but FOUR independent barrier domains for
// phase drift). Wave owns 16 tokens, sweeps full codebook, CHUNK=64,
// min4-fold (r1's best-measured sweep). B staged via global_load_lds
// (no ds_write, no reg round-trip, 1 barrier/chunk). Residual in fp32
// REGISTERS; rescore is rn-INCLUSIVE per-lane + quad-shuffle (exact ties
// preserved -> reference argmin reproduced; rn-less broke r4/r5).
// LDS union: x-stage | Bbuf dbuf | publish arrays | residual-stage.
// ---------------------------------------------------------------------------
__global__ __launch_bounds__(NTHR, 2) void rvq_fused(
        const float* __restrict__ x,            // (B, D, T)
        const float* __restrict__ cbs,          // (NCB, KSZ, DIM) fp32
        const unsigned short* __restrict__ ch,  // bf16 hi
        const float* __restrict__ cng,          // (NCB*KSZ) exact cnorm
        float* __restrict__ out,                // (B, D, T)
        float* __restrict__ codes,              // (B, NCB, T) as float
        float* __restrict__ loss_acc) {
    __shared__ __attribute__((aligned(16))) unsigned char uni[32768];
    __shared__ unsigned short best4s[T_TILE][4];           // 256 B

    unsigned short* Bb  = (unsigned short*)uni;            // sweep: 2 x 16 KB
    float*          xs  = (float*)uni;                     // init/epi: [32][128]
    float*          mv1 = (float*)uni;                     // publish: 2 KB
    float*          mv2 = (float*)(uni + 2048);            // 2 KB
    unsigned short* mi1 = (unsigned short*)(uni + 4096);   // 1 KB
    unsigned short* mi2 = (unsigned short*)(uni + 5120);   // 1 KB

    const int tid   = threadIdx.x;
    const int lane  = tid & 63;
    const int wv    = __builtin_amdgcn_readfirstlane(tid >> 6);  // 0..1
    const int col16 = lane & 15;
    const int quad  = lane >> 4;
    const int t_loc = wv * 16 + col16;   // this lane's token

    const int token0 = blockIdx.x * T_TILE;
    const int b      = token0 >> 11;
    const int t_in_b = token0 & (TOK - 1);

    // ---- init: coalesced x -> xs, then per-lane slices -> registers ----
    {
        const float* xb = x + (size_t)b * DIM * TOK + t_in_b;
#pragma unroll
        for (int it = 0; it < 8; ++it) {
            int idx = it * NTHR + tid;          // 0..1023
            int d  = idx >> 3;
            int t4 = (idx & 7) * 4;
            float4 v = *(const float4*)(xb + (size_t)d * TOK + t4);
            xs[(t4 + 0) * DIM + d] = v.x;
            xs[(t4 + 1) * DIM + d] = v.y;
            xs[(t4 + 2) * DIM + d] = v.z;
            xs[(t4 + 3) * DIM + d] = v.w;
        }
    }
    __syncthreads();

    float rr[4][8];                       // exact fp32 residual, 32 dims
#pragma unroll
    for (int dc = 0; dc < 4; ++dc) {
        float4 u = *(const float4*)&xs[t_loc * DIM + dc * 32 + quad * 8];
        float4 w = *(const float4*)&xs[t_loc * DIM + dc * 32 + quad * 8 + 4];
        rr[dc][0] = u.x; rr[dc][1] = u.y; rr[dc][2] = u.z; rr[dc][3] = u.w;
        rr[dc][4] = w.x; rr[dc][5] = w.y; rr[dc][6] = w.z; rr[dc][7] = w.w;
    }
    __syncthreads();                      // union transitions to Bbuf

    float my_loss = 0.0f;

// wave wv stages frags f = wv*8 .. wv*8+7 (f = rowgrp*4 + dimchunk) via
// global_load_lds: per-lane global src, wave-uniform LDS dst + lane*16B.
#define STAGE_GLL(bsel, cc)                                                    \
    {                                                                          \
        _Pragma("unroll")                                                      \
        for (int i = 0; i < 8; ++i) {                                          \
            int f = wv * 8 + i;                                                \
            const unsigned short* gp = ch_s +                                  \
                ((size_t)((cc) * CHUNK + (f >> 2) * 16 + col16)) * DIM +       \
                ((f & 3) * 32 + quad * 8);                                     \
            gll16(gp, Bb + (bsel) * 8192 + f * 512);                           \
        }                                                                      \
    }

// 32 MFMA over 16 tokens x 64 codes; min4-fold + single top-2 insertion.
#define COMPUTE_FOLD(cc, bsel)                                                 \
    {                                                                          \
        const unsigned short* _bh = Bb + (bsel) * 8192;                        \
        f32x4 a0 = (f32x4){0.f, 0.f, 0.f, 0.f};                                \
        f32x4 a1 = a0, a2 = a0, a3 = a0;                                       \
        __builtin_amdgcn_s_setprio(1);                                         \
        _Pragma("unroll")                                                      \
        for (int dc = 0; dc < 4; ++dc) {                                       \
            s16x8 b0 = *(const s16x8*)&_bh[(0  + dc) * 512 + lane * 8];        \
            s16x8 b1 = *(const s16x8*)&_bh[(4  + dc) * 512 + lane * 8];        \
            s16x8 b2 = *(const s16x8*)&_bh[(8  + dc) * 512 + lane * 8];        \
            s16x8 b3 = *(const s16x8*)&_bh[(12 + dc) * 512 + lane * 8];        \
            a0 = __builtin_amdgcn_mfma_f32_16x16x32_bf16(ah[dc], b0, a0, 0, 0, 0); \
            a1 = __builtin_amdgcn_mfma_f32_16x16x32_bf16(ah[dc], b1, a1, 0, 0, 0); \
            a2 = __builtin_amdgcn_mfma_f32_16x16x32_bf16(ah[dc], b2, a2, 0, 0, 0); \
            a3 = __builtin_amdgcn_mfma_f32_16x16x32_bf16(ah[dc], b3, a3, 0, 0, 0); \
            a0 = __builtin_amdgcn_mfma_f32_16x16x32_bf16(al[dc], b0, a0, 0, 0, 0); \
            a1 = __builtin_amdgcn_mfma_f32_16x16x32_bf16(al[dc], b1, a1, 0, 0, 0); \
            a2 = __builtin_amdgcn_mfma_f32_16x16x32_bf16(al[dc], b2, a2, 0, 0, 0); \
            a3 = __builtin_amdgcn_mfma_f32_16x16x32_bf16(al[dc], b3, a3, 0, 0, 0); \
        }                                                                      \
        __builtin_amdgcn_s_setprio(0);                                         \
        const int _ib0 = (cc) * CHUNK + col16;                                 \
        const float _cn0 = cn_s[_ib0], _cn1 = cn_s[_ib0 + 16];                 \
        const float _cn2 = cn_s[_ib0 + 32], _cn3 = cn_s[_ib0 + 48];            \
        _Pragma("unroll")                                                      \
        for (int r = 0; r < 4; ++r) {                                          \
            float p0 = fmaf(-2.0f, a0[r], _cn0);                               \
            float p1 = fmaf(-2.0f, a1[r], _cn1);                               \
            float p2 = fmaf(-2.0f, a2[r], _cn2);                               \
            float p3 = fmaf(-2.0f, a3[r], _cn3);                               \
            bool c01 = p1 < p0;                                                \
            float m01 = c01 ? p1 : p0; int j01 = c01 ? _ib0 + 16 : _ib0;       \
            bool c23 = p3 < p2;                                                \
            float m23 = c23 ? p3 : p2; int j23 = c23 ? _ib0 + 48 : _ib0 + 32;  \
            bool cf = m23 < m01;                                               \
            float m = cf ? m23 : m01; int jm = cf ? j23 : j01;                 \
            bool b1 = m < v1[r];                                               \
            bool b2 = m < v2[r];                                               \
            v2[r] = b1 ? v1[r] : (b2 ? m : v2[r]);                             \
            i2[r] = b1 ? i1[r] : (b2 ? jm : i2[r]);                            \
            v1[r] = b1 ? m : v1[r];                                            \
            i1[r] = b1 ? jm : i1[r];                                           \
        }                                                                      \
    }

#pragma unroll 1
    for (int s = 0; s < NCB; ++s) {
        const unsigned short* __restrict__ ch_s = ch  + (size_t)s * KSZ * DIM;
        const float* __restrict__ cb_s = cbs + (size_t)s * KSZ * DIM;
        const float* __restrict__ cn_s = cng + (size_t)s * KSZ;

        // issue chunk-0 staging; derive A-frags from registers while it flies
        STAGE_GLL(0, 0);

        s16x8 ah[4], al[4];
#pragma unroll
        for (int dc = 0; dc < 4; ++dc) {
            s16x8 hv, lv;
#pragma unroll
            for (int j = 0; j < 8; ++j) {
                unsigned short hb = f2bf(rr[dc][j]);
                hv[j] = (short)hb;
                lv[j] = (short)f2bf(rr[dc][j] - bf2f(hb));
            }
            ah[dc] = hv; al[dc] = lv;
        }

        float v1[4], v2[4]; int i1[4], i2[4];
#pragma unroll
        for (int r = 0; r < 4; ++r) {
            v1[r] = 3.4e38f; v2[r] = 3.4e38f; i1[r] = 0; i2[r] = 0;
        }

        __syncthreads();                 // chunk-0 staged (gll drained)

        // ---- sweep: 1 barrier per chunk; gll for c+1 flies under compute ----
#pragma unroll 1
        for (int cc = 0; cc < NCHUNK - 1; ++cc) {
            STAGE_GLL((cc + 1) & 1, cc + 1);
            COMPUTE_FOLD(cc, cc & 1);
            __syncthreads();             // drains my gll; all reads of cc done
        }
        COMPUTE_FOLD(NCHUNK - 1, 1);
        __syncthreads();                 // Bbuf dead -> union becomes publish

        // ---- publish per-lane top-2 (token rows of width 16) ----
#pragma unroll
        for (int r = 0; r < 4; ++r) {
            int t = wv * 16 + quad * 4 + r;
            int o = t * 16 + col16;
            mv1[o] = v1[r];
            mi1[o] = (unsigned short)i1[r];
            mv2[o] = v2[r];
            mi2[o] = (unsigned short)i2[r];
        }
        __syncthreads();

        // ---- merge 32 candidates -> top-4: 4 thr/token, 8 cands each ----
        {
            const int mt = tid >> 2;     // 0..31
            const int cs = tid & 3;
            float bv[4] = {3.4e38f, 3.4e38f, 3.4e38f, 3.4e38f};
            int   bi[4] = {0x7FFFFFFF, 0x7FFFFFFF, 0x7FFFFFFF, 0x7FFFFFFF};
            const float4  cv1 = *(const float4*)&mv1[tid * 4];
            const float4  cv2 = *(const float4*)&mv2[tid * 4];
            const ushort4 ci1 = *(const ushort4*)&mi1[tid * 4];
            const ushort4 ci2 = *(const ushort4*)&mi2[tid * 4];
            float vv[8] = {cv1.x, cv1.y, cv1.z, cv1.w,
                           cv2.x, cv2.y, cv2.z, cv2.w};
            int   ii[8] = {ci1.x, ci1.y, ci1.z, ci1.w,
                           ci2.x, ci2.y, ci2.z, ci2.w};
#pragma unroll
            for (int c = 0; c < 8; ++c) {
                float v = vv[c]; int i = ii[c];
#pragma unroll
                for (int j = 0; j < 4; ++j) {
                    if (v < bv[j] || (v == bv[j] && i < bi[j])) {
                        float tv = bv[j]; bv[j] = v; v = tv;
                        int   ti = bi[j]; bi[j] = i; i = ti;
                    }
                }
            }
#pragma unroll
            for (int mk = 1; mk <= 2; mk <<= 1) {
                float ov[4]; int oi[4];
#pragma unroll
                for (int j = 0; j < 4; ++j) {
                    ov[j] = __shfl_xor(bv[j], mk, 64);
                    oi[j] = __shfl_xor(bi[j], mk, 64);
                }
#pragma unroll
                for (int c = 0; c < 4; ++c) {
                    float v = ov[c]; int i = oi[c];
#pragma unroll
                    for (int j = 0; j < 4; ++j) {
                        if (v < bv[j] || (v == bv[j] && i < bi[j])) {
                            float tv = bv[j]; bv[j] = v; v = tv;
                            int   ti = bi[j]; bi[j] = i; i = ti;
                        }
                    }
                }
            }
            best4s[mt][cs] = (unsigned short)bi[cs];
        }
        __syncthreads();

        // ---- exact fp32 rescore, in-register, rn-INCLUSIVE ----
        {
            const int c0 = best4s[t_loc][0];
            const int c1 = best4s[t_loc][1];
            const int c2 = best4s[t_loc][2];
            const int c3 = best4s[t_loc][3];
            float rnp = 0.f;
#pragma unroll
            for (int dc = 0; dc < 4; ++dc)
#pragma unroll
                for (int j = 0; j < 8; ++j)
                    rnp = fmaf(rr[dc][j], rr[dc][j], rnp);
            float dp0 = 0.f, dp1 = 0.f, dp2 = 0.f, dp3 = 0.f;
#pragma unroll
            for (int dc = 0; dc < 4; ++dc) {
                const int doff = dc * 32 + quad * 8;
                const float4 qa0 = *(const float4*)(cb_s + (size_t)c0 * DIM + doff);
                const float4 qb0 = *(const float4*)(cb_s + (size_t)c0 * DIM + doff + 4);
                const float4 qa1 = *(const float4*)(cb_s + (size_t)c1 * DIM + doff);
                const float4 qb1 = *(const float4*)(cb_s + (size_t)c1 * DIM + doff + 4);
                const float4 qa2 = *(const float4*)(cb_s + (size_t)c2 * DIM + doff);
                const float4 qb2 = *(const float4*)(cb_s + (size_t)c2 * DIM + doff + 4);
                const float4 qa3 = *(const float4*)(cb_s + (size_t)c3 * DIM + doff);
                const float4 qb3 = *(const float4*)(cb_s + (size_t)c3 * DIM + doff + 4);
                dp0 = fmaf(rr[dc][0], qa0.x, dp0); dp0 = fmaf(rr[dc][1], qa0.y, dp0);
                dp0 = fmaf(rr[dc][2], qa0.z, dp0); dp0 = fmaf(rr[dc][3], qa0.w, dp0);
                dp0 = fmaf(rr[dc][4], qb0.x, dp0); dp0 = fmaf(rr[dc][5], qb0.y, dp0);
                dp0 = fmaf(rr[dc][6], qb0.z, dp0); dp0 = fmaf(rr[dc][7], qb0.w, dp0);
                dp1 = fmaf(rr[dc][0], qa1.x, dp1); dp1 = fmaf(rr[dc][1], qa1.y, dp1);
                dp1 = fmaf(rr[dc][2], qa1.z, dp1); dp1 = fmaf(rr[dc][3], qa1.w, dp1);
                dp1 = fmaf(rr[dc][4], qb1.x, dp1); dp1 = fmaf(rr[dc][5], qb1.y, dp1);
                dp1 = fmaf(rr[dc][6], qb1.z, dp1); dp1 = fmaf(rr[dc][7], qb1.w, dp1);
                dp2 = fmaf(rr[dc][0], qa2.x, dp2); dp2 = fmaf(rr[dc][1], qa2.y, dp2);
                dp2 = fmaf(rr[dc][2], qa2.z, dp2); dp2 = fmaf(rr[dc][3], qa2.w, dp2);
                dp2 = fmaf(rr[dc][4], qb2.x, dp2); dp2 = fmaf(rr[dc][5], qb2.y, dp2);
                dp2 = fmaf(rr[dc][6], qb2.z, dp2); dp2 = fmaf(rr[dc][7], qb2.w, dp2);
                dp3 = fmaf(rr[dc][0], qa3.x, dp3); dp3 = fmaf(rr[dc][1], qa3.y, dp3);
                dp3 = fmaf(rr[dc][2], qa3.z, dp3); dp3 = fmaf(rr[dc][3], qa3.w, dp3);
                dp3 = fmaf(rr[dc][4], qb3.x, dp3); dp3 = fmaf(rr[dc][5], qb3.y, dp3);
                dp3 = fmaf(rr[dc][6], qb3.z, dp3); dp3 = fmaf(rr[dc][7], qb3.w, dp3);
            }
            // sum over the 4 quad lanes of this token (xor 16, 32)
            rnp += __shfl_xor(rnp, 16, 64); rnp += __shfl_xor(rnp, 32, 64);
            dp0 += __shfl_xor(dp0, 16, 64); dp0 += __shfl_xor(dp0, 32, 64);
            dp1 += __shfl_xor(dp1, 16, 64); dp1 += __shfl_xor(dp1, 32, 64);
            dp2 += __shfl_xor(dp2, 16, 64); dp2 += __shfl_xor(dp2, 32, 64);
            dp3 += __shfl_xor(dp3, 16, 64); dp3 += __shfl_xor(dp3, 32, 64);
            float d0 = fmaf(-2.0f, dp0, rnp) + cn_s[c0];
            float d1 = fmaf(-2.0f, dp1, rnp) + cn_s[c1];
            float d2 = fmaf(-2.0f, dp2, rnp) + cn_s[c2];
            float d3 = fmaf(-2.0f, dp3, rnp) + cn_s[c3];
            float bd = d0; int bw = c0;
            if (d1 < bd || (d1 == bd && c1 < bw)) { bd = d1; bw = c1; }
            if (d2 < bd || (d2 == bd && c2 < bw)) { bd = d2; bw = c2; }
            if (d3 < bd || (d3 == bd && c3 < bw)) { bd = d3; bw = c3; }
            if (quad == 0)
                codes[(size_t)b * (NCB * TOK) + (size_t)s * TOK + t_in_b + t_loc] =
                    (float)bw;
            // update residual registers (exact fp32) + loss partial
            float lp = 0.0f;
#pragma unroll
            for (int dc = 0; dc < 4; ++dc) {
                const float4 qa =
                    *(const float4*)(cb_s + (size_t)bw * DIM + dc * 32 + quad * 8);
                const float4 qb =
                    *(const float4*)(cb_s + (size_t)bw * DIM + dc * 32 + quad * 8 + 4);
                float q[8] = {qa.x, qa.y, qa.z, qa.w, qb.x, qb.y, qb.z, qb.w};
#pragma unroll
                for (int j = 0; j < 8; ++j) {
                    float rf = rr[dc][j] - q[j];
                    rr[dc][j] = rf;
                    lp = fmaf(rf, rf, lp);
                }
            }
            my_loss += lp;
        }
        // no trailing barrier: next iteration's STAGE_GLL may overwrite the
        // union (publish arrays dead after merge barrier); best4s reads done
        // before any wave reaches next stage's merge (multiple barriers away);
        // the loop-top __syncthreads (after A-derive) gates the next sweep.
    }

    // ---- epilogue: rr -> xs (union), then coalesced out = x - residual ----
    __syncthreads();
#pragma unroll
    for (int dc = 0; dc < 4; ++dc) {
        *(float4*)&xs[t_loc * DIM + dc * 32 + quad * 8] =
            (float4){rr[dc][0], rr[dc][1], rr[dc][2], rr[dc][3]};
        *(float4*)&xs[t_loc * DIM + dc * 32 + quad * 8 + 4] =
            (float4){rr[dc][4], rr[dc][5], rr[dc][6], rr[dc][7]};
    }
    __syncthreads();
    {
        const float* xb = x + (size_t)b * DIM * TOK + t_in_b;
        float* ob = out + (size_t)b * DIM * TOK + t_in_b;
#pragma unroll
        for (int it = 0; it < 8; ++it) {
            int idx = it * NTHR + tid;
            int d  = idx >> 3;
            int t4 = (idx & 7) * 4;
            float4 v = *(const float4*)(xb + (size_t)d * TOK + t4);
            float4 o;
            o.x = v.x - xs[(t4 + 0) * DIM + d];
            o.y = v.y - xs[(t4 + 1) * DIM + d];
            o.z = v.z - xs[(t4 + 2) * DIM + d];
            o.w = v.w - xs[(t4 + 3) * DIM + d];
            *(float4*)(ob + (size_t)d * TOK + t4) = o;
        }
    }

    // ---- loss reduction ----
#pragma unroll
    for (int off = 32; off > 0; off >>= 1)
        my_loss += __shfl_down(my_loss, off, 64);
    if (lane == 0) atomicAdd(loss_acc, my_loss);
}

// ---------------------------------------------------------------------------
__global__ void rvq_loss_fin(const float* __restrict__ loss_acc,
                             float* __restrict__ loss_out) {
    *loss_out = *loss_acc * (1.0f / (float)NELEM);
}

// ---------------------------------------------------------------------------
extern "C" void kernel_launch(void* const* d_in, const int* in_sizes, int n_in,
                              void* d_out, int out_size, void* d_ws, size_t ws_size,
                              hipStream_t stream) {
    const float* x   = (const float*)d_in[0];   // (B, D, T)
    const float* cbs = (const float*)d_in[1];   // (NCB, KSZ, DIM)

    float* out      = (float*)d_out;
    float* codes    = out + NELEM;
    float* loss_out = out + NELEM + (size_t)BATCH * NCB * TOK;

    float* wsf      = (float*)d_ws;
    float* loss_acc = wsf;
    unsigned short* ch = (unsigned short*)(wsf + 256);
    float* cng = (float*)(ch + (size_t)NCB * KSZ * DIM);

    hipLaunchKernelGGL(rvq_prep_hi, dim3((NCB * KSZ * DIM) / 256), dim3(256),
                       0, stream, cbs, ch);
    hipLaunchKernelGGL(rvq_cnorm, dim3((NCB * KSZ) / 256), dim3(256), 0, stream,
                       cbs, cng, loss_acc);
    hipLaunchKernelGGL(rvq_fused, dim3(NTOK / T_TILE), dim3(NTHR), 0, stream,
                       x, cbs, ch, cng, out, codes, loss_acc);
    hipLaunchKernelGGL(rvq_loss_fin, dim3(1), dim3(1), 0, stream,
                       loss_acc, loss_out);
}